// Round 8
// baseline (29.376 us; speedup 1.0000x reference)
//
#include <hip/hip_runtime.h>
#include <hip/hip_cooperative_groups.h>

namespace cg = cooperative_groups;

#define DIM 128
#define LEN 256
#define INV_SQRT_D 0.08838834764831845f
#define LOG2E 1.4426950408889634f
#define SCALE_L2 (INV_SQRT_D * LOG2E)

// ws layout (floats): Mt[128*128], c[128], w2[128], bqbk[1], pad7, bf16 feat (S*D ushorts)
#define WS_MT   0
#define WS_C    (DIM * DIM)
#define WS_W2   (DIM * DIM + DIM)
#define WS_BQBK (DIM * DIM + 2 * DIM)
#define WS_BF   (DIM * DIM + 2 * DIM + 8)

__device__ __forceinline__ float bl(unsigned u) { return __uint_as_float(u << 16); }
__device__ __forceinline__ float bh(unsigned u) { return __uint_as_float(u & 0xffff0000u); }

struct MainSmem {
    float2 ibw[LEN];      // .x = idx bits, .y = mask bias (log2 units)
    float  g0L[DIM];
    float  vh[2][DIM];
    float  vL[DIM];
    float  OW[4][DIM];
    float  Zw[4];
    float  qbkL;
};

// ---- prep unit: 0..127 -> Mt row j; 128 -> c,w2,bqbk; 129.. -> bf16 convert ----
__device__ __forceinline__ void prep_unit(int unit, int t,
    const float* __restrict__ sub_feat,
    const float* __restrict__ Wq, const float* __restrict__ bq,
    const float* __restrict__ Wk, const float* __restrict__ bk,
    float* __restrict__ ws, ushort* __restrict__ bfb, int n4)
{
    if (unit < DIM) {
        __shared__ float wqj[DIM];
        if (t < DIM) wqj[t] = Wq[unit * DIM + t];
        __syncthreads();
        if (t < DIM) {
            const float4* row = reinterpret_cast<const float4*>(Wk + t * DIM);
            float acc = 0.f;
            #pragma unroll 8
            for (int i = 0; i < DIM / 4; ++i) {
                float4 u = row[i];
                acc = fmaf(u.x, wqj[4*i+0], acc);
                acc = fmaf(u.y, wqj[4*i+1], acc);
                acc = fmaf(u.z, wqj[4*i+2], acc);
                acc = fmaf(u.w, wqj[4*i+3], acc);
            }
            ws[WS_MT + unit * DIM + t] = acc;
        }
    } else if (unit == DIM) {
        __shared__ float bqs[DIM], bks[DIM], red[DIM];
        if (t < DIM) { bqs[t] = bq[t]; bks[t] = bk[t]; }
        __syncthreads();
        if (t < DIM) {
            const float4* rk = reinterpret_cast<const float4*>(Wk + t * DIM);
            const float4* rq = reinterpret_cast<const float4*>(Wq + t * DIM);
            float accC = 0.f, accW = 0.f;
            #pragma unroll 8
            for (int i = 0; i < DIM / 4; ++i) {
                float4 a  = rk[i];
                float4 b2 = rq[i];
                accC = fmaf(a.x,  bqs[4*i+0], accC);
                accC = fmaf(a.y,  bqs[4*i+1], accC);
                accC = fmaf(a.z,  bqs[4*i+2], accC);
                accC = fmaf(a.w,  bqs[4*i+3], accC);
                accW = fmaf(b2.x, bks[4*i+0], accW);
                accW = fmaf(b2.y, bks[4*i+1], accW);
                accW = fmaf(b2.z, bks[4*i+2], accW);
                accW = fmaf(b2.w, bks[4*i+3], accW);
            }
            ws[WS_C  + t] = accC;
            ws[WS_W2 + t] = accW;
            red[t] = bqs[t] * bks[t];
        }
        __syncthreads();
        if (t == 0) {
            float s = 0.f;
            for (int i = 0; i < DIM; ++i) s += red[i];
            ws[WS_BQBK] = s;
        }
    } else {
        const int i = (unit - DIM - 1) * 256 + t;
        if (i < n4) {
            const float4 u = reinterpret_cast<const float4*>(sub_feat)[i];
            ushort4 o;
            unsigned a;
            a = __float_as_uint(u.x); o.x = (ushort)((a + 0x7fffu + ((a >> 16) & 1u)) >> 16);
            a = __float_as_uint(u.y); o.y = (ushort)((a + 0x7fffu + ((a >> 16) & 1u)) >> 16);
            a = __float_as_uint(u.z); o.z = (ushort)((a + 0x7fffu + ((a >> 16) & 1u)) >> 16);
            a = __float_as_uint(u.w); o.w = (ushort)((a + 0x7fffu + ((a >> 16) & 1u)) >> 16);
            reinterpret_cast<ushort4*>(bfb)[i] = o;
        }
    }
}

// ---- stage: idx + mask bias + g0 row into LDS (independent of prep outputs) ----
__device__ __forceinline__ void stage_unit(int b, int t, MainSmem& sm,
    const float* __restrict__ sub_feat, const float* __restrict__ mask,
    const int* __restrict__ sub_index)
{
    const int   ij = sub_index[(size_t)b * LEN + t];
    const float mk = mask[(size_t)b * LEN + t];
    sm.ibw[t] = make_float2(__int_as_float(ij), (1.f - mk) * (-10000.f * LOG2E));
    if (t < 64) {
        const int r0 = sub_index[(size_t)b * LEN];
        const float2 g0p = reinterpret_cast<const float2*>(sub_feat + (size_t)r0 * DIM)[t];
        sm.g0L[2 * t]     = g0p.x;
        sm.g0L[2 * t + 1] = g0p.y;
    }
}

// ---- main phase after staging (needs a barrier-equivalent between stage and this) ----
template<bool BF16>
__device__ __forceinline__ void main_rest(int b, int t, MainSmem& sm,
    const float* __restrict__ sub_feat, const ushort* __restrict__ gfeat,
    const float* __restrict__ ws, float* __restrict__ out)
{
    const int lane = t & 63;
    const int wv   = t >> 6;
    const int g    = lane >> 4;
    const int m16  = lane & 15;

    // q0bk (wave 0) — concurrent with the matvec below, both read g0L
    if (t < 64) {
        const float* w2 = ws + WS_W2;
        float qp = sm.g0L[2 * t] * w2[2 * t] + sm.g0L[2 * t + 1] * w2[2 * t + 1];
        #pragma unroll
        for (int o = 32; o > 0; o >>= 1) qp += __shfl_xor(qp, o);
        if (t == 0) sm.qbkL = (qp + ws[WS_BQBK]) * SCALE_L2;
    }
    // cooperative matvec: vh[h][i] = sum_{j in half h} Mt[j][i]*g0[j] (coalesced over i)
    {
        const int i  = t & (DIM - 1);
        const int hh = t >> 7;
        const float* Mrow = ws + WS_MT + hh * 64 * DIM;
        const float* gL   = sm.g0L + hh * 64;
        float a = 0.f;
        #pragma unroll 8
        for (int j = 0; j < 64; ++j)
            a = fmaf(gL[j], Mrow[j * DIM + i], a);
        sm.vh[hh][i] = a;
    }
    __syncthreads();
    if (t < DIM) sm.vL[t] = (sm.vh[0][t] + sm.vh[1][t] + ws[WS_C + t]) * SCALE_L2;
    __syncthreads();

    const float4 va = reinterpret_cast<const float4*>(sm.vL)[2 * m16];
    const float4 vb = reinterpret_cast<const float4*>(sm.vL)[2 * m16 + 1];
    const float qterm = sm.qbkL;

    float Zr = 0.f;
    float O0=0.f,O1=0.f,O2=0.f,O3=0.f,O4=0.f,O5=0.f,O6=0.f,O7=0.f;

    const int jbase = wv * 64;
    #pragma unroll 4
    for (int k = 0; k < 16; ++k) {
        const float2 ibp = sm.ibw[jbase + 4 * k + g];
        const int   ij = __float_as_int(ibp.x);
        const float bj = ibp.y;
        float f0, f1, f2, f3, f4, f5, f6, f7;
        if constexpr (BF16) {
            const uint4 u = *reinterpret_cast<const uint4*>(gfeat + (size_t)ij * DIM + 8 * m16);
            f0 = bl(u.x); f1 = bh(u.x); f2 = bl(u.y); f3 = bh(u.y);
            f4 = bl(u.z); f5 = bh(u.z); f6 = bl(u.w); f7 = bh(u.w);
        } else {
            const float* rp = sub_feat + (size_t)ij * DIM + 8 * m16;
            const float4 u0 = *reinterpret_cast<const float4*>(rp);
            const float4 u1 = *reinterpret_cast<const float4*>(rp + 4);
            f0 = u0.x; f1 = u0.y; f2 = u0.z; f3 = u0.w;
            f4 = u1.x; f5 = u1.y; f6 = u1.z; f7 = u1.w;
        }
        float sd = f0*va.x + f1*va.y + f2*va.z + f3*va.w
                 + f4*vb.x + f5*vb.y + f6*vb.z + f7*vb.w;
        sd += __shfl_xor(sd, 1);
        sd += __shfl_xor(sd, 2);
        sd += __shfl_xor(sd, 4);
        sd += __shfl_xor(sd, 8);
        const float e = exp2f(sd + qterm + bj);
        Zr += e;
        O0 = fmaf(e, f0, O0); O1 = fmaf(e, f1, O1);
        O2 = fmaf(e, f2, O2); O3 = fmaf(e, f3, O3);
        O4 = fmaf(e, f4, O4); O5 = fmaf(e, f5, O5);
        O6 = fmaf(e, f6, O6); O7 = fmaf(e, f7, O7);
    }

    #pragma unroll
    for (int msk = 16; msk <= 32; msk <<= 1) {
        Zr += __shfl_xor(Zr, msk);
        O0 += __shfl_xor(O0, msk); O1 += __shfl_xor(O1, msk);
        O2 += __shfl_xor(O2, msk); O3 += __shfl_xor(O3, msk);
        O4 += __shfl_xor(O4, msk); O5 += __shfl_xor(O5, msk);
        O6 += __shfl_xor(O6, msk); O7 += __shfl_xor(O7, msk);
    }
    if (lane < 16) {
        reinterpret_cast<float4*>(&sm.OW[wv][0])[2 * m16]     = make_float4(O0, O1, O2, O3);
        reinterpret_cast<float4*>(&sm.OW[wv][0])[2 * m16 + 1] = make_float4(O4, O5, O6, O7);
    }
    if (lane == 0) sm.Zw[wv] = Zr;
    __syncthreads();

    if (t < DIM) {
        const float Zt = sm.Zw[0] + sm.Zw[1] + sm.Zw[2] + sm.Zw[3];
        out[(size_t)b * DIM + t] =
            (sm.OW[0][t] + sm.OW[1][t] + sm.OW[2][t] + sm.OW[3][t]) / Zt;
    }
}

// ---- single cooperative kernel: distributed prep -> grid sync -> per-batch main ----
__global__ __launch_bounds__(256, 8) void coop_kernel(
    const float* __restrict__ sub_feat, const float* __restrict__ mask,
    const float* __restrict__ Wq, const float* __restrict__ bq,
    const float* __restrict__ Wk, const float* __restrict__ bk,
    const int* __restrict__ sub_index, float* __restrict__ ws,
    ushort* __restrict__ bfb, float* __restrict__ out, int n4)
{
    __shared__ MainSmem sm;
    const int t   = threadIdx.x;
    const int bid = blockIdx.x;
    const int nprep = DIM + 1 + (n4 + 255) / 256;

    if (bid < nprep) prep_unit(bid, t, sub_feat, Wq, bq, Wk, bk, ws, bfb, n4);
    stage_unit(bid, t, sm, sub_feat, mask, sub_index);
    if (bid < nprep) __threadfence();
    cg::this_grid().sync();

    main_rest<true>(bid, t, sm, sub_feat, bfb, ws, out);
}

// ---- fallback path: separate prep + main kernels (R7 structure) ----
__global__ __launch_bounds__(256) void prep_kernel(
    const float* __restrict__ sub_feat,
    const float* __restrict__ Wq, const float* __restrict__ bq,
    const float* __restrict__ Wk, const float* __restrict__ bk,
    float* __restrict__ ws, ushort* __restrict__ bfb, int n4)
{
    prep_unit(blockIdx.x, threadIdx.x, sub_feat, Wq, bq, Wk, bk, ws, bfb, n4);
}

__global__ __launch_bounds__(256, 8) void main_kernel_bf16(
    const float* __restrict__ sub_feat, const ushort* __restrict__ gfeat,
    const float* __restrict__ mask, const int* __restrict__ sub_index,
    const float* __restrict__ ws, float* __restrict__ out)
{
    __shared__ MainSmem sm;
    stage_unit(blockIdx.x, threadIdx.x, sm, sub_feat, mask, sub_index);
    __syncthreads();
    main_rest<true>(blockIdx.x, threadIdx.x, sm, sub_feat, gfeat, ws, out);
}

__global__ __launch_bounds__(256, 8) void main_kernel_f32(
    const float* __restrict__ sub_feat,
    const float* __restrict__ mask, const int* __restrict__ sub_index,
    const float* __restrict__ ws, float* __restrict__ out)
{
    __shared__ MainSmem sm;
    stage_unit(blockIdx.x, threadIdx.x, sm, sub_feat, mask, sub_index);
    __syncthreads();
    main_rest<false>(blockIdx.x, threadIdx.x, sm, sub_feat, nullptr, ws, out);
}

extern "C" void kernel_launch(void* const* d_in, const int* in_sizes, int n_in,
                              void* d_out, int out_size, void* d_ws, size_t ws_size,
                              hipStream_t stream) {
    const float* sub_feat  = (const float*)d_in[0];
    const float* mask      = (const float*)d_in[1];
    const float* Wq        = (const float*)d_in[2];
    const float* bq        = (const float*)d_in[3];
    const float* Wk        = (const float*)d_in[4];
    const float* bk        = (const float*)d_in[5];
    const int*   sub_index = (const int*)d_in[6];
    float* outp = (float*)d_out;
    float* ws   = (float*)d_ws;

    const int B  = in_sizes[6] / LEN;   // 2048
    const int SD = in_sizes[0];         // S*D = 524288
    int n4 = SD / 4;
    const int nprep = DIM + 1 + (n4 + 255) / 256;

    const size_t needed = ((size_t)WS_BF + (size_t)(SD + 1) / 2) * sizeof(float);
    const bool have_bf = (ws_size >= needed);

    // decide cooperative path purely via host-side queries (capture-safe)
    bool coop = false;
    if (have_bf && B >= nprep) {
        int dev = 0;
        hipGetDevice(&dev);
        hipDeviceProp_t prop;
        if (hipGetDeviceProperties(&prop, dev) == hipSuccess && prop.cooperativeLaunch) {
            int maxb = 0;
            if (hipOccupancyMaxActiveBlocksPerMultiprocessor(
                    &maxb, reinterpret_cast<const void*>(coop_kernel), 256, 0) == hipSuccess &&
                (size_t)maxb * (size_t)prop.multiProcessorCount >= (size_t)B) {
                coop = true;
            }
        }
    }

    if (coop) {
        ushort* bfb = reinterpret_cast<ushort*>(ws + WS_BF);
        void* kargs[] = {
            (void*)&sub_feat, (void*)&mask, (void*)&Wq, (void*)&bq,
            (void*)&Wk, (void*)&bk, (void*)&sub_index, (void*)&ws,
            (void*)&bfb, (void*)&outp, (void*)&n4
        };
        hipLaunchCooperativeKernel(reinterpret_cast<const void*>(coop_kernel),
                                   dim3(B), dim3(256), kargs, 0, stream);
    } else if (have_bf) {
        ushort* bfb = reinterpret_cast<ushort*>(ws + WS_BF);
        prep_kernel<<<dim3(nprep), dim3(256), 0, stream>>>(
            sub_feat, Wq, bq, Wk, bk, ws, bfb, n4);
        main_kernel_bf16<<<dim3(B), dim3(256), 0, stream>>>(
            sub_feat, bfb, mask, sub_index, ws, outp);
    } else {
        prep_kernel<<<dim3(DIM + 1), dim3(256), 0, stream>>>(
            sub_feat, Wq, bq, Wk, bk, ws, nullptr, 0);
        main_kernel_f32<<<dim3(B), dim3(256), 0, stream>>>(
            sub_feat, mask, sub_index, ws, outp);
    }
}

// Round 9
// 27.851 us; speedup vs baseline: 1.0548x; 1.0548x over previous
//
#include <hip/hip_runtime.h>

#define DIM 128
#define LEN 256
#define INV_SQRT_D 0.08838834764831845f
#define LOG2E 1.4426950408889634f
#define SCALE_L2 (INV_SQRT_D * LOG2E)

__device__ __forceinline__ float bl(unsigned u) { return __uint_as_float(u << 16); }
__device__ __forceinline__ float bh(unsigned u) { return __uint_as_float(u & 0xffff0000u); }

struct AttnSmem {
    float2 ibw[LEN];      // .x = idx bits, .y = mask bias (log2 units)
    float  OW[4][DIM];
    float  Zw[4];
};

// ---------------- shared attention core (per-wave independent until merge) ----------------
template<bool BF16>
__device__ __forceinline__ void attn_core(
    AttnSmem& sm, int t, int b,
    const float4& va, const float4& vb, float qterm,
    const float* __restrict__ sub_feat, const ushort* __restrict__ gfeat,
    float* __restrict__ out)
{
    const int lane = t & 63;
    const int wv   = t >> 6;
    const int g    = lane >> 4;
    const int m16  = lane & 15;

    float Zr = 0.f;
    float O0=0.f,O1=0.f,O2=0.f,O3=0.f,O4=0.f,O5=0.f,O6=0.f,O7=0.f;

    const int jbase = wv * 64;
    #pragma unroll 4
    for (int k = 0; k < 16; ++k) {
        const float2 ibp = sm.ibw[jbase + 4 * k + g];
        const int   ij = __float_as_int(ibp.x);
        const float bj = ibp.y;
        float f0, f1, f2, f3, f4, f5, f6, f7;
        if constexpr (BF16) {
            const uint4 u = *reinterpret_cast<const uint4*>(gfeat + (size_t)ij * DIM + 8 * m16);
            f0 = bl(u.x); f1 = bh(u.x); f2 = bl(u.y); f3 = bh(u.y);
            f4 = bl(u.z); f5 = bh(u.z); f6 = bl(u.w); f7 = bh(u.w);
        } else {
            const float* rp = sub_feat + (size_t)ij * DIM + 8 * m16;
            const float4 u0 = *reinterpret_cast<const float4*>(rp);
            const float4 u1 = *reinterpret_cast<const float4*>(rp + 4);
            f0 = u0.x; f1 = u0.y; f2 = u0.z; f3 = u0.w;
            f4 = u1.x; f5 = u1.y; f6 = u1.z; f7 = u1.w;
        }
        float sd = f0*va.x + f1*va.y + f2*va.z + f3*va.w
                 + f4*vb.x + f5*vb.y + f6*vb.z + f7*vb.w;
        sd += __shfl_xor(sd, 1);
        sd += __shfl_xor(sd, 2);
        sd += __shfl_xor(sd, 4);
        sd += __shfl_xor(sd, 8);
        const float e = exp2f(sd + qterm + bj);
        Zr += e;
        O0 = fmaf(e, f0, O0); O1 = fmaf(e, f1, O1);
        O2 = fmaf(e, f2, O2); O3 = fmaf(e, f3, O3);
        O4 = fmaf(e, f4, O4); O5 = fmaf(e, f5, O5);
        O6 = fmaf(e, f6, O6); O7 = fmaf(e, f7, O7);
    }

    #pragma unroll
    for (int msk = 16; msk <= 32; msk <<= 1) {
        Zr += __shfl_xor(Zr, msk);
        O0 += __shfl_xor(O0, msk); O1 += __shfl_xor(O1, msk);
        O2 += __shfl_xor(O2, msk); O3 += __shfl_xor(O3, msk);
        O4 += __shfl_xor(O4, msk); O5 += __shfl_xor(O5, msk);
        O6 += __shfl_xor(O6, msk); O7 += __shfl_xor(O7, msk);
    }
    if (lane < 16) {
        reinterpret_cast<float4*>(&sm.OW[wv][0])[2 * m16]     = make_float4(O0, O1, O2, O3);
        reinterpret_cast<float4*>(&sm.OW[wv][0])[2 * m16 + 1] = make_float4(O4, O5, O6, O7);
    }
    if (lane == 0) sm.Zw[wv] = Zr;
    __syncthreads();

    if (t < DIM) {
        const float Zt = sm.Zw[0] + sm.Zw[1] + sm.Zw[2] + sm.Zw[3];
        out[(size_t)b * DIM + t] =
            (sm.OW[0][t] + sm.OW[1][t] + sm.OW[2][t] + sm.OW[3][t]) / Zt;
    }
}

// ---------------- D1: vq (8 batches/block, no Mt) + bf16 convert ----------------
__global__ __launch_bounds__(256) void prep2_kernel(
    const float* __restrict__ sub_feat, const int* __restrict__ sub_index,
    const float* __restrict__ Wq, const float* __restrict__ bq,
    const float* __restrict__ Wk, const float* __restrict__ bk,
    float* __restrict__ vout, float* __restrict__ qout,
    ushort* __restrict__ bfb, int n4, int B, int nv)
{
    const int t   = threadIdx.x;
    const int bid = blockIdx.x;

    if (bid >= nv) {
        // bf16 convert (RNE)
        const int i = (bid - nv) * 256 + t;
        if (i < n4) {
            const float4 u = reinterpret_cast<const float4*>(sub_feat)[i];
            ushort4 o;
            unsigned a;
            a = __float_as_uint(u.x); o.x = (ushort)((a + 0x7fffu + ((a >> 16) & 1u)) >> 16);
            a = __float_as_uint(u.y); o.y = (ushort)((a + 0x7fffu + ((a >> 16) & 1u)) >> 16);
            a = __float_as_uint(u.z); o.z = (ushort)((a + 0x7fffu + ((a >> 16) & 1u)) >> 16);
            a = __float_as_uint(u.w); o.w = (ushort)((a + 0x7fffu + ((a >> 16) & 1u)) >> 16);
            reinterpret_cast<ushort4*>(bfb)[i] = o;
        }
        return;
    }

    const int lane = t & 63;
    const int wv   = t >> 6;
    const int b0   = bid * 8;

    __shared__ float g0[8][DIM];
    __shared__ float ph[2][8][DIM];
    __shared__ float q0[8][DIM];

    // stage 8 g0 rows (wave w loads rows 2w, 2w+1)
    #pragma unroll
    for (int s = 0; s < 2; ++s) {
        const int bb = wv * 2 + s;
        const int b  = b0 + bb;
        if (b < B) {
            const int r0 = sub_index[(size_t)b * LEN];
            const float2 p = reinterpret_cast<const float2*>(sub_feat + (size_t)r0 * DIM)[lane];
            g0[bb][2 * lane]     = p.x;
            g0[bb][2 * lane + 1] = p.y;
        } else {
            g0[bb][2 * lane] = 0.f; g0[bb][2 * lane + 1] = 0.f;
        }
    }
    __syncthreads();

    const int d = t & (DIM - 1);
    const int h = t >> 7;

    // q0[b][d] = sum_e g0[b][e] * Wq[e][d] + bq[d]   (coalesced over d)
    {
        float acc[8] = {0.f,0.f,0.f,0.f,0.f,0.f,0.f,0.f};
        const int e0 = h * 64;
        #pragma unroll 4
        for (int e = e0; e < e0 + 64; ++e) {
            const float w = Wq[e * DIM + d];
            #pragma unroll
            for (int bb = 0; bb < 8; ++bb) acc[bb] = fmaf(g0[bb][e], w, acc[bb]);
        }
        #pragma unroll
        for (int bb = 0; bb < 8; ++bb) ph[h][bb][d] = acc[bb];
    }
    __syncthreads();
    if (h == 0) {
        #pragma unroll
        for (int bb = 0; bb < 8; ++bb) q0[bb][d] = ph[0][bb][d] + ph[1][bb][d] + bq[d];
    }
    __syncthreads();

    // q0bk[b] = q0[b] . bk  (wave w handles batches 2w, 2w+1), pre-scaled
    #pragma unroll
    for (int s = 0; s < 2; ++s) {
        const int bb = wv * 2 + s;
        float p = q0[bb][lane] * bk[lane] + q0[bb][lane + 64] * bk[lane + 64];
        #pragma unroll
        for (int o = 32; o > 0; o >>= 1) p += __shfl_xor(p, o);
        if (lane == 0 && b0 + bb < B) qout[b0 + bb] = p * SCALE_L2;
    }

    // v[b][i] = sum_d Wk[i][d] * q0[b][d]   (thread owns row i = d, streams it)
    {
        float acc[8] = {0.f,0.f,0.f,0.f,0.f,0.f,0.f,0.f};
        const int d0 = h * 64;
        const float* wrow = Wk + (size_t)d * DIM + d0;
        #pragma unroll 4
        for (int dd = 0; dd < 64; ++dd) {
            const float w = wrow[dd];
            #pragma unroll
            for (int bb = 0; bb < 8; ++bb) acc[bb] = fmaf(w, q0[bb][d0 + dd], acc[bb]);
        }
        #pragma unroll
        for (int bb = 0; bb < 8; ++bb) ph[h][bb][d] = acc[bb];
    }
    __syncthreads();
    if (h == 0) {
        #pragma unroll
        for (int bb = 0; bb < 8; ++bb) {
            if (b0 + bb < B)
                vout[(size_t)(b0 + bb) * DIM + d] = (ph[0][bb][d] + ph[1][bb][d]) * SCALE_L2;
        }
    }
}

// ---------------- D2: attention, 1 block = 1 batch ----------------
__global__ __launch_bounds__(256, 8) void attn_bf16_kernel(
    const ushort* __restrict__ gfeat, const float* __restrict__ mask,
    const int* __restrict__ sub_index, const float* __restrict__ vbuf,
    const float* __restrict__ qbuf, float* __restrict__ out)
{
    __shared__ AttnSmem sm;
    const int t = threadIdx.x;
    const int b = blockIdx.x;
    const int m16 = (t & 63) & 15;

    const int   ij = sub_index[(size_t)b * LEN + t];
    const float mk = mask[(size_t)b * LEN + t];
    sm.ibw[t] = make_float2(__int_as_float(ij), (1.f - mk) * (-10000.f * LOG2E));

    const float4 va = reinterpret_cast<const float4*>(vbuf + (size_t)b * DIM)[2 * m16];
    const float4 vb = reinterpret_cast<const float4*>(vbuf + (size_t)b * DIM)[2 * m16 + 1];
    const float qterm = qbuf[b];

    // no barrier: each wave reads only its own ibw segment (wave-ordered LDS)
    attn_core<true>(sm, t, b, va, vb, qterm, nullptr, gfeat, out);
}

__global__ __launch_bounds__(256, 8) void attn_f32_kernel(
    const float* __restrict__ sub_feat, const float* __restrict__ mask,
    const int* __restrict__ sub_index, const float* __restrict__ vbuf,
    const float* __restrict__ qbuf, float* __restrict__ out)
{
    __shared__ AttnSmem sm;
    const int t = threadIdx.x;
    const int b = blockIdx.x;
    const int m16 = (t & 63) & 15;

    const int   ij = sub_index[(size_t)b * LEN + t];
    const float mk = mask[(size_t)b * LEN + t];
    sm.ibw[t] = make_float2(__int_as_float(ij), (1.f - mk) * (-10000.f * LOG2E));

    const float4 va = reinterpret_cast<const float4*>(vbuf + (size_t)b * DIM)[2 * m16];
    const float4 vb = reinterpret_cast<const float4*>(vbuf + (size_t)b * DIM)[2 * m16 + 1];
    const float qterm = qbuf[b];

    attn_core<false>(sm, t, b, va, vb, qterm, sub_feat, nullptr, out);
}

// ---------------- tier C: fully self-contained (no workspace) ----------------
__global__ __launch_bounds__(256) void mono_kernel(
    const float* __restrict__ sub_feat, const float* __restrict__ mask,
    const int* __restrict__ sub_index,
    const float* __restrict__ Wq, const float* __restrict__ bq,
    const float* __restrict__ Wk, const float* __restrict__ bk,
    float* __restrict__ out)
{
    const int t    = threadIdx.x;
    const int lane = t & 63;
    const int b    = blockIdx.x;
    const int m16  = lane & 15;

    __shared__ AttnSmem sm;
    __shared__ float g0L[DIM];
    __shared__ float ph[2][DIM];
    __shared__ float q0L[DIM];
    __shared__ float vL[DIM];
    __shared__ float qbkL;

    {
        const int   ij = sub_index[(size_t)b * LEN + t];
        const float mk = mask[(size_t)b * LEN + t];
        sm.ibw[t] = make_float2(__int_as_float(ij), (1.f - mk) * (-10000.f * LOG2E));
    }
    if (t < 64) {
        const int r0 = sub_index[(size_t)b * LEN];
        const float2 p = reinterpret_cast<const float2*>(sub_feat + (size_t)r0 * DIM)[t];
        g0L[2 * t] = p.x; g0L[2 * t + 1] = p.y;
    }
    __syncthreads();

    const int d = t & (DIM - 1);
    const int h = t >> 7;
    {
        float a = 0.f;
        const int e0 = h * 64;
        #pragma unroll 4
        for (int e = e0; e < e0 + 64; ++e) a = fmaf(g0L[e], Wq[e * DIM + d], a);
        ph[h][d] = a;
    }
    __syncthreads();
    if (h == 0) q0L[d] = ph[0][d] + ph[1][d] + bq[d];
    __syncthreads();
    if (t < 64) {
        float p = q0L[t] * bk[t] + q0L[t + 64] * bk[t + 64];
        #pragma unroll
        for (int o = 32; o > 0; o >>= 1) p += __shfl_xor(p, o);
        if (t == 0) qbkL = p * SCALE_L2;
    }
    {
        float a = 0.f;
        const int d0 = h * 64;
        const float* wr = Wk + (size_t)d * DIM + d0;
        #pragma unroll 4
        for (int dd = 0; dd < 64; ++dd) a = fmaf(wr[dd], q0L[d0 + dd], a);
        ph[h][d] = a;
    }
    __syncthreads();
    if (h == 0) vL[d] = (ph[0][d] + ph[1][d]) * SCALE_L2;
    __syncthreads();

    const float4 va = reinterpret_cast<const float4*>(vL)[2 * m16];
    const float4 vb = reinterpret_cast<const float4*>(vL)[2 * m16 + 1];
    attn_core<false>(sm, t, b, va, vb, qbkL, sub_feat, nullptr, out);
}

extern "C" void kernel_launch(void* const* d_in, const int* in_sizes, int n_in,
                              void* d_out, int out_size, void* d_ws, size_t ws_size,
                              hipStream_t stream) {
    const float* sub_feat  = (const float*)d_in[0];
    const float* mask      = (const float*)d_in[1];
    const float* Wq        = (const float*)d_in[2];
    const float* bq        = (const float*)d_in[3];
    const float* Wk        = (const float*)d_in[4];
    const float* bk        = (const float*)d_in[5];
    const int*   sub_index = (const int*)d_in[6];
    float* outp = (float*)d_out;
    float* ws   = (float*)d_ws;

    const int B  = in_sizes[6] / LEN;   // 2048
    const int SD = in_sizes[0];         // S*D = 524288
    const int n4 = SD / 4;
    const int nv = (B + 7) / 8;         // 256 vq blocks
    const int ncv = (n4 + 255) / 256;   // 512 convert blocks

    const size_t vq_floats  = (size_t)B * DIM + (size_t)B;
    const size_t need_vq    = vq_floats * sizeof(float);
    const size_t need_full  = need_vq + (size_t)SD * sizeof(ushort);

    float*  vbuf = ws;
    float*  qbuf = ws + (size_t)B * DIM;
    ushort* bfb  = reinterpret_cast<ushort*>(ws + vq_floats);

    if (ws_size >= need_full) {
        prep2_kernel<<<dim3(nv + ncv), dim3(256), 0, stream>>>(
            sub_feat, sub_index, Wq, bq, Wk, bk, vbuf, qbuf, bfb, n4, B, nv);
        attn_bf16_kernel<<<dim3(B), dim3(256), 0, stream>>>(
            bfb, mask, sub_index, vbuf, qbuf, outp);
    } else if (ws_size >= need_vq) {
        prep2_kernel<<<dim3(nv), dim3(256), 0, stream>>>(
            sub_feat, sub_index, Wq, bq, Wk, bk, vbuf, qbuf, nullptr, 0, B, nv);
        attn_f32_kernel<<<dim3(B), dim3(256), 0, stream>>>(
            sub_feat, mask, sub_index, vbuf, qbuf, outp);
    } else {
        mono_kernel<<<dim3(B), dim3(256), 0, stream>>>(
            sub_feat, mask, sub_index, Wq, bq, Wk, bk, outp);
    }
}